// Round 16
// baseline (258.875 us; speedup 1.0000x reference)
//
#include <hip/hip_runtime.h>
#include <hip/hip_bf16.h>

typedef __bf16 bf16_t;
typedef __bf16 bf16x8 __attribute__((ext_vector_type(8)));
typedef float f32x4 __attribute__((ext_vector_type(4)));

constexpr int Bz = 8, Lseq = 1024, Dm = 512, Hh = 8, DKd = 64;
constexpr int MTOK = Bz * Lseq;   // 8192 tokens
constexpr int NREL = 201;
constexpr int PROW = 202;         // padded LDS row (bank stride 101%32=5, coprime)

// pos pre-scale: 0.125 (1/sqrt(dk)) * log2(e), folded so p = exp2(st*C + pos)
#define POS_C 0.18033688011112042f

__device__ inline float fexp2(float x) {
#if __has_builtin(__builtin_amdgcn_exp2f)
  return __builtin_amdgcn_exp2f(x);
#else
  return exp2f(x);
#endif
}
__device__ inline float b2f(unsigned short u) {
  return __builtin_bit_cast(float, (unsigned)u << 16);
}
__device__ inline unsigned pack2(float a, float b) {
  unsigned short ua = __builtin_bit_cast(unsigned short, (bf16_t)a);
  unsigned short ub = __builtin_bit_cast(unsigned short, (bf16_t)b);
  return (unsigned)ua | ((unsigned)ub << 16);
}
__device__ inline bf16x8 cvt8(const float* __restrict__ p) {
  float4 x = *reinterpret_cast<const float4*>(p);
  float4 y = *reinterpret_cast<const float4*>(p + 4);
  bf16x8 r;
  r[0] = (bf16_t)x.x; r[1] = (bf16_t)x.y; r[2] = (bf16_t)x.z; r[3] = (bf16_t)x.w;
  r[4] = (bf16_t)y.x; r[5] = (bf16_t)y.y; r[6] = (bf16_t)y.z; r[7] = (bf16_t)y.w;
  return r;
}

// ---------------- one-launch cast of Wq,Wk,Wv,Wfc + rel ----------------------
__global__ __launch_bounds__(256) void k_castw(
    const float* __restrict__ s0, const float* __restrict__ s1,
    const float* __restrict__ s2, const float* __restrict__ s3,
    const float* __restrict__ s4, bf16_t* __restrict__ d0,
    bf16_t* __restrict__ d1, bf16_t* __restrict__ d2, bf16_t* __restrict__ d3,
    bf16_t* __restrict__ d4) {
  const int y = blockIdx.y;
  const float* s = y == 0 ? s0 : y == 1 ? s1 : y == 2 ? s2 : y == 3 ? s3 : s4;
  bf16_t* d = y == 0 ? d0 : y == 1 ? d1 : y == 2 ? d2 : y == 3 ? d3 : d4;
  const int n = y < 4 ? Dm * Dm : NREL * DKd;
  int i = (blockIdx.x * 256 + threadIdx.x) * 4;
  if (i + 3 < n) {
    float4 v = *reinterpret_cast<const float4*>(s + i);
    d[i + 0] = (bf16_t)v.x;
    d[i + 1] = (bf16_t)v.y;
    d[i + 2] = (bf16_t)v.z;
    d[i + 3] = (bf16_t)v.w;
  } else if (i < n) {
    for (; i < n; ++i) d[i] = (bf16_t)s[i];
  }
}

// ---------------- projection: y = (fp32 A) @ W^T, fused cast ------------------
// Template instantiation per input (no runtime pointer select -> normal
// codegen, unlike r11). Chunked XCD swizzle: each XCD owns contiguous
// row-blocks so each fp32 A row-panel is fetched by exactly ONE XCD's L2
// (r11's 197MB cross-XCD refetch -> ~33MB).
// MODE 0: bf16 head-major (Q,K); MODE 1: bf16 head-transposed (V).
template <int MODE>
__global__ __launch_bounds__(256) void k_projf(const float* __restrict__ A,
                                               const bf16_t* __restrict__ W,
                                               bf16_t* __restrict__ outb) {
  const int lane = threadIdx.x & 63, w = threadIdx.x >> 6;
  const int lr = lane & 15, lg = lane >> 4;
  // bijective chunked XCD swizzle (nwg=1024, chunk=128)
  const int orig = blockIdx.x + blockIdx.y * 8;
  const int swz = ((orig & 7) << 7) | (orig >> 3);
  const int Rbase = (swz >> 3) * 64 + (w >> 1) * 32;
  const int Cbase = (swz & 7) * 64 + (w & 1) * 32;

  f32x4 acc[2][2] = {};
  for (int k0 = 0; k0 < Dm; k0 += 32) {
    bf16x8 af[2], wf[2];
#pragma unroll
    for (int i = 0; i < 2; ++i)
      af[i] = cvt8(A + (size_t)(Rbase + i * 16 + lr) * Dm + k0 + lg * 8);
#pragma unroll
    for (int j = 0; j < 2; ++j)
      wf[j] = *reinterpret_cast<const bf16x8*>(W + (size_t)(Cbase + j * 16 + lr) * Dm + k0 + lg * 8);
#pragma unroll
    for (int i = 0; i < 2; ++i)
#pragma unroll
      for (int j = 0; j < 2; ++j)
        acc[i][j] = __builtin_amdgcn_mfma_f32_16x16x32_bf16(af[i], wf[j], acc[i][j], 0, 0, 0);
  }
#pragma unroll
  for (int i = 0; i < 2; ++i)
#pragma unroll
    for (int j = 0; j < 2; ++j)
#pragma unroll
      for (int r = 0; r < 4; ++r) {
        const int gr = Rbase + i * 16 + lg * 4 + r;  // token row
        const int gc = Cbase + j * 16 + lr;          // output col
        const int bb = gr >> 10, qq = gr & 1023, hh = gc >> 6, dd = gc & 63;
        const bf16_t vv = (bf16_t)acc[i][j][r];
        if (MODE == 0)
          outb[(((size_t)(bb * Hh + hh)) * Lseq + qq) * DKd + dd] = vv;
        else
          outb[(((size_t)(bb * Hh + hh)) * DKd + dd) * Lseq + qq] = vv;
      }
}

// ---------------- fc GEMM: yf = attnb @ Wfc^T + resid (fp32) ------------------
__global__ __launch_bounds__(256) void k_fc(const bf16_t* __restrict__ A,
                                            const bf16_t* __restrict__ W,
                                            float* __restrict__ outf,
                                            const float* __restrict__ resid) {
  const int lane = threadIdx.x & 63, w = threadIdx.x >> 6;
  const int lr = lane & 15, lg = lane >> 4;
  // bijective chunked XCD swizzle (nwg=1024, chunk=128)
  const int orig = blockIdx.x + blockIdx.y * 8;
  const int swz = ((orig & 7) << 7) | (orig >> 3);
  const int Rbase = (swz >> 3) * 64 + (w >> 1) * 32;
  const int Cbase = (swz & 7) * 64 + (w & 1) * 32;

  f32x4 acc[2][2] = {};
  for (int k0 = 0; k0 < Dm; k0 += 32) {
    bf16x8 af[2], wf[2];
#pragma unroll
    for (int i = 0; i < 2; ++i)
      af[i] = *reinterpret_cast<const bf16x8*>(A + (size_t)(Rbase + i * 16 + lr) * Dm + k0 + lg * 8);
#pragma unroll
    for (int j = 0; j < 2; ++j)
      wf[j] = *reinterpret_cast<const bf16x8*>(W + (size_t)(Cbase + j * 16 + lr) * Dm + k0 + lg * 8);
#pragma unroll
    for (int i = 0; i < 2; ++i)
#pragma unroll
      for (int j = 0; j < 2; ++j)
        acc[i][j] = __builtin_amdgcn_mfma_f32_16x16x32_bf16(af[i], wf[j], acc[i][j], 0, 0, 0);
  }
#pragma unroll
  for (int i = 0; i < 2; ++i)
#pragma unroll
    for (int j = 0; j < 2; ++j)
#pragma unroll
      for (int r = 0; r < 4; ++r) {
        const int gr = Rbase + i * 16 + lg * 4 + r;
        const int gc = Cbase + j * 16 + lr;
        const size_t idx = (size_t)gr * Dm + gc;
        outf[idx] = acc[i][j][r] + resid[idx];
      }
}

// ---------------- flash attention + fused in-block posdot (r15: 84us) ---------
__global__ __launch_bounds__(256, 4) void k_attn(const bf16_t* __restrict__ Qh,
                                                 const bf16_t* __restrict__ Kh,
                                                 const bf16_t* __restrict__ Vt,
                                                 const bf16_t* __restrict__ relb,
                                                 bf16_t* __restrict__ attnb) {
  __shared__ float smemf[6528];   // pos 12928B + Pl 10240B = 23168B; Ml 26112B

  const int tid = threadIdx.x;
  const int wv = tid >> 6, lane = tid & 63;
  const int lr = lane & 15, lg = lane >> 4;
  // bijective chunked XCD swizzle (nwg=2048, chunk=256)
  const int gid = ((blockIdx.x & 7) << 8) | (blockIdx.x >> 3);
  const int bh = gid >> 5;
  const int qb = (gid & 31) << 5;             // 32-row q tile

  unsigned short* pls = reinterpret_cast<unsigned short*>(smemf);     // [32][202]
  unsigned* Pw = reinterpret_cast<unsigned*>(smemf) + 3232 + wv * 640; // [2][16][20]

  const bf16_t* Qp = Qh + ((size_t)bh * Lseq + qb) * DKd;
  const bf16_t* Kp = Kh + (size_t)bh * Lseq * DKd;
  const bf16_t* Vp = Vt + (size_t)bh * DKd * Lseq;

  // Q fragments (dual-use: B-operand for swapped QK^T, A-operand for posdot)
  bf16x8 qf[2][2];
#pragma unroll
  for (int t = 0; t < 2; ++t)
#pragma unroll
    for (int h = 0; h < 2; ++h)
      qf[t][h] = *reinterpret_cast<const bf16x8*>(Qp + (size_t)(t * 16 + lr) * DKd + h * 32 + lg * 8);

  // ---- in-block posdot: pls[q][200-r] = POS_C * dot(Q[q], rel[r]) -----------
  for (int n = wv; n < 13; n += 4) {
    const int rr0 = n * 16 + lr;
    const int rclamp = rr0 > 200 ? 200 : rr0;
    bf16x8 rf0 = *reinterpret_cast<const bf16x8*>(relb + (size_t)rclamp * DKd + lg * 8);
    bf16x8 rf1 = *reinterpret_cast<const bf16x8*>(relb + (size_t)rclamp * DKd + 32 + lg * 8);
#pragma unroll
    for (int t = 0; t < 2; ++t) {
      f32x4 st = {};
      st = __builtin_amdgcn_mfma_f32_16x16x32_bf16(qf[t][0], rf0, st, 0, 0, 0);
      st = __builtin_amdgcn_mfma_f32_16x16x32_bf16(qf[t][1], rf1, st, 0, 0, 0);
      if (rr0 <= 200) {
#pragma unroll
        for (int r = 0; r < 4; ++r)
          pls[(t * 16 + lg * 4 + r) * PROW + (200 - rr0)] =
              __builtin_bit_cast(unsigned short, (bf16_t)(st[r] * POS_C));
      }
    }
  }
  __syncthreads();

  // per-lane pos row bases + band-edge constants (already scaled by POS_C)
  const unsigned short* prow[2] = {pls + (size_t)lr * PROW,
                                   pls + (size_t)(16 + lr) * PROW};
  float pe0[2], pe200[2];
#pragma unroll
  for (int t = 0; t < 2; ++t) {
    pe0[t] = b2f(prow[t][0]);       // k <= q-100 side
    pe200[t] = b2f(prow[t][200]);   // k >= q+100 side
  }

  f32x4 Oacc[2][4] = {};
  float psum[2] = {0.f, 0.f};
  const int ldelta = lg * 4 - lr;

  const int kbase = wv * 256;
#pragma unroll 2
  for (int k0 = kbase; k0 < kbase + 256; k0 += 32) {
    bf16x8 kf[2][2];
#pragma unroll
    for (int u = 0; u < 2; ++u)
#pragma unroll
      for (int h = 0; h < 2; ++h)
        kf[u][h] = *reinterpret_cast<const bf16x8*>(Kp + (size_t)(k0 + u * 16 + lr) * DKd + h * 32 + lg * 8);

#pragma unroll
    for (int t = 0; t < 2; ++t) {
      const int Qt = qb + t * 16;
      f32x4 st[2];
#pragma unroll
      for (int u = 0; u < 2; ++u) {
        f32x4 a = {};
        a = __builtin_amdgcn_mfma_f32_16x16x32_bf16(kf[u][0], qf[t][0], a, 0, 0, 0);
        a = __builtin_amdgcn_mfma_f32_16x16x32_bf16(kf[u][1], qf[t][1], a, 0, 0, 0);
        st[u] = a;  // element: q = Qt+lr (col), k = k0+u*16+lg*4+r (row)
      }
      float p[2][4];
      if (k0 + 131 <= Qt) {            // whole step below band: pos = pls[q][0]
#pragma unroll
        for (int u = 0; u < 2; ++u)
#pragma unroll
          for (int r = 0; r < 4; ++r)
            p[u][r] = fexp2(fmaf(st[u][r], POS_C, pe0[t]));
      } else if (k0 >= Qt + 115) {     // whole step above band: pos = pls[q][200]
#pragma unroll
        for (int u = 0; u < 2; ++u)
#pragma unroll
          for (int r = 0; r < 4; ++r)
            p[u][r] = fexp2(fmaf(st[u][r], POS_C, pe200[t]));
      } else {                         // in-band: clamped gather from LDS
#pragma unroll
        for (int u = 0; u < 2; ++u) {
          const int jb = k0 + u * 16 + 100 - Qt + ldelta;
#pragma unroll
          for (int r = 0; r < 4; ++r) {
            int j = jb + r;
            j = j < 0 ? 0 : (j > 200 ? 200 : j);
            p[u][r] = fexp2(fmaf(st[u][r], POS_C, b2f(prow[t][j])));
          }
        }
      }
#pragma unroll
      for (int u = 0; u < 2; ++u)
#pragma unroll
        for (int r = 0; r < 4; ++r) psum[t] += p[u][r];
      // pack to bf16, wave-private LDS transpose (D-layout -> B-frag layout)
#pragma unroll
      for (int u = 0; u < 2; ++u) {
        uint2 pk;
        pk.x = pack2(p[u][0], p[u][1]);
        pk.y = pack2(p[u][2], p[u][3]);
        *reinterpret_cast<uint2*>(&Pw[t * 320 + lr * 20 + u * 8 + lg * 2]) = pk;
      }
    }
    // PV: A = Vt fragment, B = P fragment read back from LDS
    bf16x8 pb[2];
#pragma unroll
    for (int t = 0; t < 2; ++t)
      pb[t] = *reinterpret_cast<const bf16x8*>(&Pw[t * 320 + lr * 20 + lg * 4]);
#pragma unroll
    for (int f = 0; f < 4; ++f) {
      bf16x8 vf = *reinterpret_cast<const bf16x8*>(Vp + (size_t)(f * 16 + lr) * Lseq + k0 + lg * 8);
#pragma unroll
      for (int t = 0; t < 2; ++t)
        Oacc[t][f] = __builtin_amdgcn_mfma_f32_16x16x32_bf16(vf, pb[t], Oacc[t][f], 0, 0, 0);
    }
  }

  // ---- merge the four k-quarters (no-max partials combine by pure addition) --
  __syncthreads();   // k-loops done; pos+Pl dead -> reuse smem as Ml[3][64][34]
  float* Ml = smemf;
  if (wv) {
    float* m = Ml + ((wv - 1) * 64 + lane) * 34;
#pragma unroll
    for (int t = 0; t < 2; ++t)
#pragma unroll
      for (int f = 0; f < 4; ++f)
#pragma unroll
        for (int r = 0; r < 4; ++r) m[t * 16 + f * 4 + r] = Oacc[t][f][r];
    m[32] = psum[0];
    m[33] = psum[1];
  }
  __syncthreads();
  if (!wv) {
#pragma unroll
    for (int w2 = 0; w2 < 3; ++w2) {
      const float* m = Ml + (w2 * 64 + lane) * 34;
#pragma unroll
      for (int t = 0; t < 2; ++t) {
#pragma unroll
        for (int f = 0; f < 4; ++f)
#pragma unroll
          for (int r = 0; r < 4; ++r) Oacc[t][f][r] += m[t * 16 + f * 4 + r];
        psum[t] += m[32 + t];
      }
    }
    const int gb = bh >> 3, hh = bh & 7;
#pragma unroll
    for (int t = 0; t < 2; ++t) {
      float s = psum[t];
      s += __shfl_xor(s, 16);
      s += __shfl_xor(s, 32);
      const float inv = 1.0f / s;
      const int qg = qb + t * 16 + lr;
#pragma unroll
      for (int f = 0; f < 4; ++f) {
        uint2 ov;
        ov.x = pack2(Oacc[t][f][0] * inv, Oacc[t][f][1] * inv);
        ov.y = pack2(Oacc[t][f][2] * inv, Oacc[t][f][3] * inv);
        *reinterpret_cast<uint2*>(attnb + ((size_t)(gb * Lseq + qg)) * Dm + hh * DKd + f * 16 + lg * 4) = ov;
      }
    }
  }
}

// ---------------- row LayerNorm over D=512 (near BW-roofline: ~4.9 TB/s) ------
__global__ __launch_bounds__(256) void k_ln(const float* __restrict__ y,
                                            const float* __restrict__ g,
                                            const float* __restrict__ be,
                                            float* __restrict__ out) {
  const int row = blockIdx.x * 4 + (threadIdx.x >> 6);
  const int lane = threadIdx.x & 63;
  const float* yp = y + (size_t)row * Dm + lane * 8;
  float4 v0 = *reinterpret_cast<const float4*>(yp);
  float4 v1 = *reinterpret_cast<const float4*>(yp + 4);
  float vv[8] = {v0.x, v0.y, v0.z, v0.w, v1.x, v1.y, v1.z, v1.w};
  float s = 0.f, s2 = 0.f;
#pragma unroll
  for (int j = 0; j < 8; ++j) { s += vv[j]; s2 += vv[j] * vv[j]; }
  for (int mk = 1; mk < 64; mk <<= 1) {
    s += __shfl_xor(s, mk, 64);
    s2 += __shfl_xor(s2, mk, 64);
  }
  const float mu = s * (1.0f / Dm);
  const float var = s2 * (1.0f / Dm) - mu * mu;
  const float inv = rsqrtf(var + 1e-6f);
  float* op = out + (size_t)row * Dm + lane * 8;
  const float* gp = g + lane * 8;
  const float* bp = be + lane * 8;
#pragma unroll
  for (int j = 0; j < 8; ++j) op[j] = (vv[j] - mu) * inv * gp[j] + bp[j];
}

// ------------------------------------------------------------------------------
extern "C" void kernel_launch(void* const* d_in, const int* in_sizes, int n_in,
                              void* d_out, int out_size, void* d_ws, size_t ws_size,
                              hipStream_t stream) {
  const float* q   = (const float*)d_in[0];
  const float* k   = (const float*)d_in[1];
  const float* v   = (const float*)d_in[2];
  const float* Wq  = (const float*)d_in[3];
  const float* Wk  = (const float*)d_in[4];
  const float* Wv  = (const float*)d_in[5];
  const float* Wfc = (const float*)d_in[6];
  const float* rel = (const float*)d_in[7];
  const float* gam = (const float*)d_in[8];
  const float* bet = (const float*)d_in[9];

  char* ws = (char*)d_ws;
  size_t off = 0;
  auto take = [&](size_t bytes) {
    char* p = ws + off;
    off += (bytes + 255) & ~(size_t)255;
    return p;
  };
  bf16_t* wqb  = (bf16_t*)take((size_t)Dm * Dm * 2);
  bf16_t* wkb  = (bf16_t*)take((size_t)Dm * Dm * 2);
  bf16_t* wvb  = (bf16_t*)take((size_t)Dm * Dm * 2);
  bf16_t* wfcb = (bf16_t*)take((size_t)Dm * Dm * 2);
  bf16_t* relb = (bf16_t*)take((size_t)NREL * DKd * 2);
  bf16_t* Qhp  = (bf16_t*)take((size_t)MTOK * Dm * 2);
  bf16_t* Khp  = (bf16_t*)take((size_t)MTOK * Dm * 2);
  bf16_t* Vtp  = (bf16_t*)take((size_t)MTOK * Dm * 2);
  bf16_t* attnb= (bf16_t*)take((size_t)MTOK * Dm * 2);
  float*  yf   = (float*)take((size_t)MTOK * Dm * 4);

  // 1) weights + rel cast (one launch)
  k_castw<<<dim3(Dm * Dm / 1024, 5), 256, 0, stream>>>(
      Wq, Wk, Wv, Wfc, rel, wqb, wkb, wvb, wfcb, relb);
  // 2) projections: fp32 A directly, fused cast (template per input)
  dim3 gg(Dm / 64, MTOK / 64);
  k_projf<0><<<gg, 256, 0, stream>>>(q, wqb, Qhp);
  k_projf<0><<<gg, 256, 0, stream>>>(k, wkb, Khp);
  k_projf<1><<<gg, 256, 0, stream>>>(v, wvb, Vtp);
  // 3) attention (posdot fused in-block; r15: 84us)
  k_attn<<<dim3(2048), 256, 0, stream>>>(Qhp, Khp, Vtp, relb, attnb);
  // 4) output GEMM + residual (fp32 yf)
  k_fc<<<gg, 256, 0, stream>>>(attnb, wfcb, yf, q);
  // 5) LayerNorm
  k_ln<<<dim3(MTOK / 4), 256, 0, stream>>>(yf, gam, bet, (float*)d_out);
}

// Round 17
// 228.635 us; speedup vs baseline: 1.1323x; 1.1323x over previous
//
#include <hip/hip_runtime.h>
#include <hip/hip_bf16.h>

typedef __bf16 bf16_t;
typedef __bf16 bf16x8 __attribute__((ext_vector_type(8)));
typedef float f32x4 __attribute__((ext_vector_type(4)));

constexpr int Bz = 8, Lseq = 1024, Dm = 512, Hh = 8, DKd = 64;
constexpr int MTOK = Bz * Lseq;   // 8192 tokens
constexpr int NREL = 201;
constexpr int PROW = 202;         // padded LDS row (bank stride 101%32=5, coprime)

// pos pre-scale: 0.125 (1/sqrt(dk)) * log2(e), folded so p = exp2(st*C + pos)
#define POS_C 0.18033688011112042f

__device__ inline float fexp2(float x) {
#if __has_builtin(__builtin_amdgcn_exp2f)
  return __builtin_amdgcn_exp2f(x);
#else
  return exp2f(x);
#endif
}
__device__ inline float b2f(unsigned short u) {
  return __builtin_bit_cast(float, (unsigned)u << 16);
}
__device__ inline unsigned pack2(float a, float b) {
  unsigned short ua = __builtin_bit_cast(unsigned short, (bf16_t)a);
  unsigned short ub = __builtin_bit_cast(unsigned short, (bf16_t)b);
  return (unsigned)ua | ((unsigned)ub << 16);
}

// ---------------- one-launch cast of Wq,Wk,Wv,Wfc + rel ----------------------
__global__ __launch_bounds__(256) void k_castw(
    const float* __restrict__ s0, const float* __restrict__ s1,
    const float* __restrict__ s2, const float* __restrict__ s3,
    const float* __restrict__ s4, bf16_t* __restrict__ d0,
    bf16_t* __restrict__ d1, bf16_t* __restrict__ d2, bf16_t* __restrict__ d3,
    bf16_t* __restrict__ d4) {
  const int y = blockIdx.y;
  const float* s = y == 0 ? s0 : y == 1 ? s1 : y == 2 ? s2 : y == 3 ? s3 : s4;
  bf16_t* d = y == 0 ? d0 : y == 1 ? d1 : y == 2 ? d2 : y == 3 ? d3 : d4;
  const int n = y < 4 ? Dm * Dm : NREL * DKd;
  int i = (blockIdx.x * 256 + threadIdx.x) * 4;
  if (i + 3 < n) {
    float4 v = *reinterpret_cast<const float4*>(s + i);
    d[i + 0] = (bf16_t)v.x;
    d[i + 1] = (bf16_t)v.y;
    d[i + 2] = (bf16_t)v.z;
    d[i + 3] = (bf16_t)v.w;
  } else if (i < n) {
    for (; i < n; ++i) d[i] = (bf16_t)s[i];
  }
}

// ---------------- one-launch cast of q,k,v: 8 elems/thread, 16B stores --------
__global__ __launch_bounds__(256) void k_castx(
    const float* __restrict__ s0, const float* __restrict__ s1,
    const float* __restrict__ s2, bf16_t* __restrict__ d0,
    bf16_t* __restrict__ d1, bf16_t* __restrict__ d2) {
  const int y = blockIdx.y;
  const float* s = y == 0 ? s0 : y == 1 ? s1 : s2;
  bf16_t* d = y == 0 ? d0 : y == 1 ? d1 : d2;
  const int i = (blockIdx.x * 256 + threadIdx.x) * 8;
  float4 a = *reinterpret_cast<const float4*>(s + i);
  float4 b = *reinterpret_cast<const float4*>(s + i + 4);
  bf16x8 r;
  r[0] = (bf16_t)a.x; r[1] = (bf16_t)a.y; r[2] = (bf16_t)a.z; r[3] = (bf16_t)a.w;
  r[4] = (bf16_t)b.x; r[5] = (bf16_t)b.y; r[6] = (bf16_t)b.z; r[7] = (bf16_t)b.w;
  *reinterpret_cast<bf16x8*>(d + i) = r;
}

// ---------------- y = A @ W^T  (A:[8192][512] bf16, W:[512][512] bf16) --------
// MODE 0: bf16 head-major; MODE 1: bf16 head-transposed.
template <int MODE>
__global__ __launch_bounds__(256) void k_gemm512(const bf16_t* __restrict__ A,
                                                 const bf16_t* __restrict__ W,
                                                 bf16_t* __restrict__ outb) {
  const int lane = threadIdx.x & 63, w = threadIdx.x >> 6;
  const int lr = lane & 15, lg = lane >> 4;
  // bijective chunked XCD swizzle (nwg=1024, chunk=128)
  const int orig = blockIdx.x + blockIdx.y * 8;
  const int swz = ((orig & 7) << 7) | (orig >> 3);
  const int Rbase = (swz >> 3) * 64 + (w >> 1) * 32;
  const int Cbase = (swz & 7) * 64 + (w & 1) * 32;

  f32x4 acc[2][2] = {};
  for (int k0 = 0; k0 < Dm; k0 += 32) {
    bf16x8 af[2], wf[2];
#pragma unroll
    for (int i = 0; i < 2; ++i)
      af[i] = *reinterpret_cast<const bf16x8*>(A + (size_t)(Rbase + i * 16 + lr) * Dm + k0 + lg * 8);
#pragma unroll
    for (int j = 0; j < 2; ++j)
      wf[j] = *reinterpret_cast<const bf16x8*>(W + (size_t)(Cbase + j * 16 + lr) * Dm + k0 + lg * 8);
#pragma unroll
    for (int i = 0; i < 2; ++i)
#pragma unroll
      for (int j = 0; j < 2; ++j)
        acc[i][j] = __builtin_amdgcn_mfma_f32_16x16x32_bf16(af[i], wf[j], acc[i][j], 0, 0, 0);
  }
#pragma unroll
  for (int i = 0; i < 2; ++i)
#pragma unroll
    for (int j = 0; j < 2; ++j)
#pragma unroll
      for (int r = 0; r < 4; ++r) {
        const int gr = Rbase + i * 16 + lg * 4 + r;  // token row
        const int gc = Cbase + j * 16 + lr;          // output col
        const int bb = gr >> 10, qq = gr & 1023, hh = gc >> 6, dd = gc & 63;
        const bf16_t vv = (bf16_t)acc[i][j][r];
        if (MODE == 0)
          outb[(((size_t)(bb * Hh + hh)) * Lseq + qq) * DKd + dd] = vv;
        else
          outb[(((size_t)(bb * Hh + hh)) * DKd + dd) * Lseq + qq] = vv;
      }
}

// ---------------- fc GEMM: yf = attnb @ Wfc^T + resid (fp32) ------------------
__global__ __launch_bounds__(256) void k_fc(const bf16_t* __restrict__ A,
                                            const bf16_t* __restrict__ W,
                                            float* __restrict__ outf,
                                            const float* __restrict__ resid) {
  const int lane = threadIdx.x & 63, w = threadIdx.x >> 6;
  const int lr = lane & 15, lg = lane >> 4;
  // bijective chunked XCD swizzle (nwg=1024, chunk=128)
  const int orig = blockIdx.x + blockIdx.y * 8;
  const int swz = ((orig & 7) << 7) | (orig >> 3);
  const int Rbase = (swz >> 3) * 64 + (w >> 1) * 32;
  const int Cbase = (swz & 7) * 64 + (w & 1) * 32;

  f32x4 acc[2][2] = {};
  for (int k0 = 0; k0 < Dm; k0 += 32) {
    bf16x8 af[2], wf[2];
#pragma unroll
    for (int i = 0; i < 2; ++i)
      af[i] = *reinterpret_cast<const bf16x8*>(A + (size_t)(Rbase + i * 16 + lr) * Dm + k0 + lg * 8);
#pragma unroll
    for (int j = 0; j < 2; ++j)
      wf[j] = *reinterpret_cast<const bf16x8*>(W + (size_t)(Cbase + j * 16 + lr) * Dm + k0 + lg * 8);
#pragma unroll
    for (int i = 0; i < 2; ++i)
#pragma unroll
      for (int j = 0; j < 2; ++j)
        acc[i][j] = __builtin_amdgcn_mfma_f32_16x16x32_bf16(af[i], wf[j], acc[i][j], 0, 0, 0);
  }
#pragma unroll
  for (int i = 0; i < 2; ++i)
#pragma unroll
    for (int j = 0; j < 2; ++j)
#pragma unroll
      for (int r = 0; r < 4; ++r) {
        const int gr = Rbase + i * 16 + lg * 4 + r;
        const int gc = Cbase + j * 16 + lr;
        const size_t idx = (size_t)gr * Dm + gc;
        outf[idx] = acc[i][j][r] + resid[idx];
      }
}

// ---------------- flash attention + fused in-block posdot (r15: 84us) ---------
__global__ __launch_bounds__(256, 4) void k_attn(const bf16_t* __restrict__ Qh,
                                                 const bf16_t* __restrict__ Kh,
                                                 const bf16_t* __restrict__ Vt,
                                                 const bf16_t* __restrict__ relb,
                                                 bf16_t* __restrict__ attnb) {
  __shared__ float smemf[6528];   // pos 12928B + Pl 10240B = 23168B; Ml 26112B

  const int tid = threadIdx.x;
  const int wv = tid >> 6, lane = tid & 63;
  const int lr = lane & 15, lg = lane >> 4;
  // bijective chunked XCD swizzle (nwg=2048, chunk=256)
  const int gid = ((blockIdx.x & 7) << 8) | (blockIdx.x >> 3);
  const int bh = gid >> 5;
  const int qb = (gid & 31) << 5;             // 32-row q tile

  unsigned short* pls = reinterpret_cast<unsigned short*>(smemf);     // [32][202]
  unsigned* Pw = reinterpret_cast<unsigned*>(smemf) + 3232 + wv * 640; // [2][16][20]

  const bf16_t* Qp = Qh + ((size_t)bh * Lseq + qb) * DKd;
  const bf16_t* Kp = Kh + (size_t)bh * Lseq * DKd;
  const bf16_t* Vp = Vt + (size_t)bh * DKd * Lseq;

  // Q fragments (dual-use: B-operand for swapped QK^T, A-operand for posdot)
  bf16x8 qf[2][2];
#pragma unroll
  for (int t = 0; t < 2; ++t)
#pragma unroll
    for (int h = 0; h < 2; ++h)
      qf[t][h] = *reinterpret_cast<const bf16x8*>(Qp + (size_t)(t * 16 + lr) * DKd + h * 32 + lg * 8);

  // ---- in-block posdot: pls[q][200-r] = POS_C * dot(Q[q], rel[r]) -----------
  for (int n = wv; n < 13; n += 4) {
    const int rr0 = n * 16 + lr;
    const int rclamp = rr0 > 200 ? 200 : rr0;
    bf16x8 rf0 = *reinterpret_cast<const bf16x8*>(relb + (size_t)rclamp * DKd + lg * 8);
    bf16x8 rf1 = *reinterpret_cast<const bf16x8*>(relb + (size_t)rclamp * DKd + 32 + lg * 8);
#pragma unroll
    for (int t = 0; t < 2; ++t) {
      f32x4 st = {};
      st = __builtin_amdgcn_mfma_f32_16x16x32_bf16(qf[t][0], rf0, st, 0, 0, 0);
      st = __builtin_amdgcn_mfma_f32_16x16x32_bf16(qf[t][1], rf1, st, 0, 0, 0);
      if (rr0 <= 200) {
#pragma unroll
        for (int r = 0; r < 4; ++r)
          pls[(t * 16 + lg * 4 + r) * PROW + (200 - rr0)] =
              __builtin_bit_cast(unsigned short, (bf16_t)(st[r] * POS_C));
      }
    }
  }
  __syncthreads();

  // per-lane pos row bases + band-edge constants (already scaled by POS_C)
  const unsigned short* prow[2] = {pls + (size_t)lr * PROW,
                                   pls + (size_t)(16 + lr) * PROW};
  float pe0[2], pe200[2];
#pragma unroll
  for (int t = 0; t < 2; ++t) {
    pe0[t] = b2f(prow[t][0]);       // k <= q-100 side
    pe200[t] = b2f(prow[t][200]);   // k >= q+100 side
  }

  f32x4 Oacc[2][4] = {};
  float psum[2] = {0.f, 0.f};
  const int ldelta = lg * 4 - lr;

  const int kbase = wv * 256;
#pragma unroll 2
  for (int k0 = kbase; k0 < kbase + 256; k0 += 32) {
    bf16x8 kf[2][2];
#pragma unroll
    for (int u = 0; u < 2; ++u)
#pragma unroll
      for (int h = 0; h < 2; ++h)
        kf[u][h] = *reinterpret_cast<const bf16x8*>(Kp + (size_t)(k0 + u * 16 + lr) * DKd + h * 32 + lg * 8);

#pragma unroll
    for (int t = 0; t < 2; ++t) {
      const int Qt = qb + t * 16;
      f32x4 st[2];
#pragma unroll
      for (int u = 0; u < 2; ++u) {
        f32x4 a = {};
        a = __builtin_amdgcn_mfma_f32_16x16x32_bf16(kf[u][0], qf[t][0], a, 0, 0, 0);
        a = __builtin_amdgcn_mfma_f32_16x16x32_bf16(kf[u][1], qf[t][1], a, 0, 0, 0);
        st[u] = a;  // element: q = Qt+lr (col), k = k0+u*16+lg*4+r (row)
      }
      float p[2][4];
      if (k0 + 131 <= Qt) {            // whole step below band: pos = pls[q][0]
#pragma unroll
        for (int u = 0; u < 2; ++u)
#pragma unroll
          for (int r = 0; r < 4; ++r)
            p[u][r] = fexp2(fmaf(st[u][r], POS_C, pe0[t]));
      } else if (k0 >= Qt + 115) {     // whole step above band: pos = pls[q][200]
#pragma unroll
        for (int u = 0; u < 2; ++u)
#pragma unroll
          for (int r = 0; r < 4; ++r)
            p[u][r] = fexp2(fmaf(st[u][r], POS_C, pe200[t]));
      } else {                         // in-band: clamped gather from LDS
#pragma unroll
        for (int u = 0; u < 2; ++u) {
          const int jb = k0 + u * 16 + 100 - Qt + ldelta;
#pragma unroll
          for (int r = 0; r < 4; ++r) {
            int j = jb + r;
            j = j < 0 ? 0 : (j > 200 ? 200 : j);
            p[u][r] = fexp2(fmaf(st[u][r], POS_C, b2f(prow[t][j])));
          }
        }
      }
#pragma unroll
      for (int u = 0; u < 2; ++u)
#pragma unroll
        for (int r = 0; r < 4; ++r) psum[t] += p[u][r];
      // pack to bf16, wave-private LDS transpose (D-layout -> B-frag layout)
#pragma unroll
      for (int u = 0; u < 2; ++u) {
        uint2 pk;
        pk.x = pack2(p[u][0], p[u][1]);
        pk.y = pack2(p[u][2], p[u][3]);
        *reinterpret_cast<uint2*>(&Pw[t * 320 + lr * 20 + u * 8 + lg * 2]) = pk;
      }
    }
    // PV: A = Vt fragment, B = P fragment read back from LDS
    bf16x8 pb[2];
#pragma unroll
    for (int t = 0; t < 2; ++t)
      pb[t] = *reinterpret_cast<const bf16x8*>(&Pw[t * 320 + lr * 20 + lg * 4]);
#pragma unroll
    for (int f = 0; f < 4; ++f) {
      bf16x8 vf = *reinterpret_cast<const bf16x8*>(Vp + (size_t)(f * 16 + lr) * Lseq + k0 + lg * 8);
#pragma unroll
      for (int t = 0; t < 2; ++t)
        Oacc[t][f] = __builtin_amdgcn_mfma_f32_16x16x32_bf16(vf, pb[t], Oacc[t][f], 0, 0, 0);
    }
  }

  // ---- merge the four k-quarters (no-max partials combine by pure addition) --
  __syncthreads();   // k-loops done; pos+Pl dead -> reuse smem as Ml[3][64][34]
  float* Ml = smemf;
  if (wv) {
    float* m = Ml + ((wv - 1) * 64 + lane) * 34;
#pragma unroll
    for (int t = 0; t < 2; ++t)
#pragma unroll
      for (int f = 0; f < 4; ++f)
#pragma unroll
        for (int r = 0; r < 4; ++r) m[t * 16 + f * 4 + r] = Oacc[t][f][r];
    m[32] = psum[0];
    m[33] = psum[1];
  }
  __syncthreads();
  if (!wv) {
#pragma unroll
    for (int w2 = 0; w2 < 3; ++w2) {
      const float* m = Ml + (w2 * 64 + lane) * 34;
#pragma unroll
      for (int t = 0; t < 2; ++t) {
#pragma unroll
        for (int f = 0; f < 4; ++f)
#pragma unroll
          for (int r = 0; r < 4; ++r) Oacc[t][f][r] += m[t * 16 + f * 4 + r];
        psum[t] += m[32 + t];
      }
    }
    const int gb = bh >> 3, hh = bh & 7;
#pragma unroll
    for (int t = 0; t < 2; ++t) {
      float s = psum[t];
      s += __shfl_xor(s, 16);
      s += __shfl_xor(s, 32);
      const float inv = 1.0f / s;
      const int qg = qb + t * 16 + lr;
#pragma unroll
      for (int f = 0; f < 4; ++f) {
        uint2 ov;
        ov.x = pack2(Oacc[t][f][0] * inv, Oacc[t][f][1] * inv);
        ov.y = pack2(Oacc[t][f][2] * inv, Oacc[t][f][3] * inv);
        *reinterpret_cast<uint2*>(attnb + ((size_t)(gb * Lseq + qg)) * Dm + hh * DKd + f * 16 + lg * 4) = ov;
      }
    }
  }
}

// ---------------- row LayerNorm over D=512 (near BW-roofline: ~4.9 TB/s) ------
__global__ __launch_bounds__(256) void k_ln(const float* __restrict__ y,
                                            const float* __restrict__ g,
                                            const float* __restrict__ be,
                                            float* __restrict__ out) {
  const int row = blockIdx.x * 4 + (threadIdx.x >> 6);
  const int lane = threadIdx.x & 63;
  const float* yp = y + (size_t)row * Dm + lane * 8;
  float4 v0 = *reinterpret_cast<const float4*>(yp);
  float4 v1 = *reinterpret_cast<const float4*>(yp + 4);
  float vv[8] = {v0.x, v0.y, v0.z, v0.w, v1.x, v1.y, v1.z, v1.w};
  float s = 0.f, s2 = 0.f;
#pragma unroll
  for (int j = 0; j < 8; ++j) { s += vv[j]; s2 += vv[j] * vv[j]; }
  for (int mk = 1; mk < 64; mk <<= 1) {
    s += __shfl_xor(s, mk, 64);
    s2 += __shfl_xor(s2, mk, 64);
  }
  const float mu = s * (1.0f / Dm);
  const float var = s2 * (1.0f / Dm) - mu * mu;
  const float inv = rsqrtf(var + 1e-6f);
  float* op = out + (size_t)row * Dm + lane * 8;
  const float* gp = g + lane * 8;
  const float* bp = be + lane * 8;
#pragma unroll
  for (int j = 0; j < 8; ++j) op[j] = (vv[j] - mu) * inv * gp[j] + bp[j];
}

// ------------------------------------------------------------------------------
extern "C" void kernel_launch(void* const* d_in, const int* in_sizes, int n_in,
                              void* d_out, int out_size, void* d_ws, size_t ws_size,
                              hipStream_t stream) {
  const float* q   = (const float*)d_in[0];
  const float* k   = (const float*)d_in[1];
  const float* v   = (const float*)d_in[2];
  const float* Wq  = (const float*)d_in[3];
  const float* Wk  = (const float*)d_in[4];
  const float* Wv  = (const float*)d_in[5];
  const float* Wfc = (const float*)d_in[6];
  const float* rel = (const float*)d_in[7];
  const float* gam = (const float*)d_in[8];
  const float* bet = (const float*)d_in[9];

  char* ws = (char*)d_ws;
  size_t off = 0;
  auto take = [&](size_t bytes) {
    char* p = ws + off;
    off += (bytes + 255) & ~(size_t)255;
    return p;
  };
  bf16_t* wqb  = (bf16_t*)take((size_t)Dm * Dm * 2);
  bf16_t* wkb  = (bf16_t*)take((size_t)Dm * Dm * 2);
  bf16_t* wvb  = (bf16_t*)take((size_t)Dm * Dm * 2);
  bf16_t* wfcb = (bf16_t*)take((size_t)Dm * Dm * 2);
  bf16_t* relb = (bf16_t*)take((size_t)NREL * DKd * 2);
  bf16_t* qb   = (bf16_t*)take((size_t)MTOK * Dm * 2);
  bf16_t* kb   = (bf16_t*)take((size_t)MTOK * Dm * 2);
  bf16_t* vb   = (bf16_t*)take((size_t)MTOK * Dm * 2);
  bf16_t* Qhp  = (bf16_t*)take((size_t)MTOK * Dm * 2);
  bf16_t* Khp  = (bf16_t*)take((size_t)MTOK * Dm * 2);
  bf16_t* Vtp  = (bf16_t*)take((size_t)MTOK * Dm * 2);
  bf16_t* attnb= (bf16_t*)take((size_t)MTOK * Dm * 2);
  float*  yf   = (float*)take((size_t)MTOK * Dm * 4);

  // 1) weights + rel cast (one launch)
  k_castw<<<dim3(Dm * Dm / 1024, 5), 256, 0, stream>>>(
      Wq, Wk, Wv, Wfc, rel, wqb, wkb, wvb, wfcb, relb);
  // 2) q/k/v cast (one launch, 8 elems/thread)
  k_castx<<<dim3(MTOK * Dm / 2048, 3), 256, 0, stream>>>(
      q, k, v, qb, kb, vb);
  // 3) projections (bf16 A path — proven fastest)
  dim3 gg(Dm / 64, MTOK / 64);
  k_gemm512<0><<<gg, 256, 0, stream>>>(qb, wqb, Qhp);
  k_gemm512<0><<<gg, 256, 0, stream>>>(kb, wkb, Khp);
  k_gemm512<1><<<gg, 256, 0, stream>>>(vb, wvb, Vtp);
  // 4) attention (posdot fused in-block; r15: 84us)
  k_attn<<<dim3(2048), 256, 0, stream>>>(Qhp, Khp, Vtp, relb, attnb);
  // 5) output GEMM + residual (fp32 yf)
  k_fc<<<gg, 256, 0, stream>>>(attnb, wfcb, yf, q);
  // 6) LayerNorm
  k_ln<<<dim3(MTOK / 4), 256, 0, stream>>>(yf, gam, bet, (float*)d_out);
}